// Round 2
// baseline (588.874 us; speedup 1.0000x reference)
//
#include <hip/hip_runtime.h>

typedef __bf16 bf16;
typedef __bf16 bf16x4 __attribute__((ext_vector_type(4)));
typedef __bf16 bf16x8 __attribute__((ext_vector_type(8)));
typedef float f32x4 __attribute__((ext_vector_type(4)));

#define MFMA(a, b, c) __builtin_amdgcn_mfma_f32_16x16x32_bf16(a, b, c, 0, 0, 0)

// async global->LDS, 16B per lane. HW constraint: LDS dest is wave-uniform
// base (readfirstlane) + lane*16, so the per-lane lds ptr MUST equal that.
__device__ __forceinline__ void gload_lds16(const void* g, void* l) {
  __builtin_amdgcn_global_load_lds(
      (const __attribute__((address_space(1))) void*)g,
      (__attribute__((address_space(3))) void*)l, 16, 0, 0);
}

// ---------------------------------------------------------------------------
// fp32 -> bf16 converter, 4 elems/thread, n must be a multiple of 4.
// ---------------------------------------------------------------------------
__global__ __launch_bounds__(256) void cvt_bf16(const float* __restrict__ in,
                                                bf16* __restrict__ out, int n) {
  int i = (blockIdx.x * 256 + threadIdx.x) * 4;
  if (i >= n) return;
  float4 v = *(const float4*)(in + i);
  bf16x4 o = {(bf16)v.x, (bf16)v.y, (bf16)v.z, (bf16)v.w};
  *(bf16x4*)(out + i) = o;
}

// ---------------------------------------------------------------------------
// v_weight [4096,2048] fp32 -> vt [2048,4096] bf16 (vt[hd][m] = v[m][hd]).
// 64x64 tiles via LDS, coalesced both sides.
// ---------------------------------------------------------------------------
__global__ __launch_bounds__(256) void transpose_v_cvt(const float* __restrict__ v,
                                                       bf16* __restrict__ vt) {
  __shared__ bf16 T[64 * 72];  // 144B row stride (16B-aligned), breaks bank stride
  const int m0 = blockIdx.x * 64, c0 = blockIdx.y * 64;
  const int tid = threadIdx.x;
  const int tr = tid >> 3;        // 0..31
  const int tc = (tid & 7) << 3;  // 0,8,...,56
#pragma unroll
  for (int it = 0; it < 2; it++) {
    int r = tr + it * 32;
    const float* src = v + (long)(m0 + r) * 2048 + c0 + tc;
    float4 a = *(const float4*)src;
    float4 b = *(const float4*)(src + 4);
    bf16x8 t = {(bf16)a.x, (bf16)a.y, (bf16)a.z, (bf16)a.w,
                (bf16)b.x, (bf16)b.y, (bf16)b.z, (bf16)b.w};
    *(bf16x8*)&T[r * 72 + tc] = t;
  }
  __syncthreads();
#pragma unroll
  for (int it = 0; it < 2; it++) {
    int c = tr + it * 32;
    bf16x8 o;
#pragma unroll
    for (int j = 0; j < 8; j++) o[j] = T[(tc + j) * 72 + c];
    *(bf16x8*)(vt + (long)(c0 + c) * 4096 + m0 + tc) = o;
  }
}

// ---------------------------------------------------------------------------
// m97-style NT GEMM: C[M,N] = A[M,K] * B[N,K]^T, bf16 in, fp32 accum.
// MODE 0: C=result (bf16). MODE 1: C=silu(result)*other (bf16).
// MODE 2: C=result (fp32 out).
// 128x128 tile, BK=32, 256 threads (4 waves as 2x2 of 64x64).
// ---------------------------------------------------------------------------
template <int MODE>
__global__ __launch_bounds__(256, 2) void gemm_bt(const bf16* __restrict__ A,
                                                  const bf16* __restrict__ B,
                                                  const bf16* __restrict__ other,
                                                  bf16* __restrict__ Cb,
                                                  float* __restrict__ Cf, int M, int N, int K) {
  __shared__ bf16 As[128 * 32];
  __shared__ bf16 Bs[128 * 32];
  const int tid = threadIdx.x;
  const int wave = tid >> 6, lane = tid & 63;
  const int wr = wave >> 1, wc = wave & 1;
  const long bM = (long)blockIdx.y * 128, bN = (long)blockIdx.x * 128;

  f32x4 acc[4][4] = {};

  // staging: wave w covers rows [w*32, w*32+32) in 2 instrs of 16 rows each;
  // per-lane lds addr == wave base + lane*16  (global_load_lds constraint)
  const int srow = (wave << 5) + (lane >> 2);
  const int scol = (lane & 3) << 3;
  const bf16* Ag = A + (bM + srow) * (long)K + scol;
  const bf16* Bg = B + (bN + srow) * (long)K + scol;
  bf16* Asl = &As[srow * 32 + scol];
  bf16* Bsl = &Bs[srow * 32 + scol];

  const int fr = lane & 15;         // fragment row
  const int fk = (lane >> 4) << 3;  // fragment k offset

  for (int k0 = 0; k0 < K; k0 += 32) {
    __syncthreads();
    gload_lds16(Ag + k0, Asl);
    gload_lds16(Ag + k0 + (long)16 * K, Asl + 16 * 32);
    gload_lds16(Bg + k0, Bsl);
    gload_lds16(Bg + k0 + (long)16 * K, Bsl + 16 * 32);
    __syncthreads();
    bf16x8 af[4], bfv[4];
#pragma unroll
    for (int i = 0; i < 4; i++)
      af[i] = *(const bf16x8*)&As[(wr * 64 + i * 16 + fr) * 32 + fk];
#pragma unroll
    for (int j = 0; j < 4; j++)
      bfv[j] = *(const bf16x8*)&Bs[(wc * 64 + j * 16 + fr) * 32 + fk];
#pragma unroll
    for (int i = 0; i < 4; i++)
#pragma unroll
      for (int j = 0; j < 4; j++) acc[i][j] = MFMA(af[i], bfv[j], acc[i][j]);
  }

  // C/D layout: col = lane&15, row = (lane>>4)*4 + reg
  const int er = wr * 64 + ((lane >> 4) << 2);
  const int ec = wc * 64 + (lane & 15);
#pragma unroll
  for (int i = 0; i < 4; i++)
#pragma unroll
    for (int j = 0; j < 4; j++)
#pragma unroll
      for (int r = 0; r < 4; r++) {
        long row = bM + er + i * 16 + r;
        long col = bN + ec + j * 16;
        float v = acc[i][j][r];
        if (MODE == 1) {
          float g = v / (1.f + __expf(-v));  // silu
          v = g * (float)other[row * (long)N + col];
        }
        if (MODE == 2)
          Cf[row * (long)N + col] = v;
        else
          Cb[row * (long)N + col] = (bf16)v;
      }
}

// ---------------------------------------------------------------------------
// Fused attention (no softmax): per (b,h,ntile): O = scale*(silu(scale*Q Kh^T) @ Vh),
// streamed over M in 64-row chunks. Q frags live in registers for the block.
// P round-trips through LDS (C-layout -> A-layout). V comes pre-transposed.
// ---------------------------------------------------------------------------
__global__ __launch_bounds__(256, 2) void attn_fused(const bf16* __restrict__ q,
                                                     const bf16* __restrict__ kw,
                                                     const bf16* __restrict__ vt,
                                                     bf16* __restrict__ attn) {
  constexpr int E = 2048, M = 4096, NQ = 2048;
  constexpr float scale = 11.3137085f;  // sqrt(dk)=sqrt(128)
  const int nt = blockIdx.x, bh = blockIdx.y;
  const int b = bh >> 4, h = bh & 15;
  const int tid = threadIdx.x, wave = tid >> 6, lane = tid & 63;
  const int wr = wave >> 1, wc = wave & 1;
  const int fr = lane & 15, fk = (lane >> 4) << 3;

  __shared__ bf16 Ks[64 * 128];   // [m][d]   16KB
  __shared__ bf16 Vts[128 * 64];  // [dv][m]  16KB
  __shared__ bf16 Ps[128 * 64];   // [n][m]   16KB

  // Q fragments: wave's 64 n-rows x dk=128 (4 k-steps) — loaded once
  const bf16* qbase = q + (long)(b * NQ + nt * 128) * E + h * 128;
  bf16x8 qf[4][4];
#pragma unroll
  for (int i = 0; i < 4; i++)
#pragma unroll
    for (int ks = 0; ks < 4; ks++)
      qf[i][ks] = *(const bf16x8*)(qbase + (long)(wr * 64 + i * 16 + fr) * E + ks * 32 + fk);

  f32x4 oacc[4][4] = {};

  // staging (per-lane lds addr == wave base + lane*16 in both)
  const int krow = (wave << 4) + (lane >> 4);
  const int kcol = (lane & 15) << 3;
  const int vrow = (wave << 5) + (lane >> 3);
  const int vcol = (lane & 7) << 3;
  const bf16* kg = kw + (long)krow * E + h * 128 + kcol;
  const bf16* vg = vt + (long)(h * 128 + vrow) * M + vcol;
  bf16* ksl = &Ks[krow * 128 + kcol];
  bf16* vsl = &Vts[vrow * 64 + vcol];

  for (int m0 = 0; m0 < M; m0 += 64) {
    __syncthreads();
#pragma unroll
    for (int i = 0; i < 4; i++) {
      gload_lds16(kg + (long)(m0 + i * 4) * E, ksl + i * 4 * 128);
      gload_lds16(vg + m0 + (long)i * 8 * M, vsl + i * 8 * 64);
    }
    __syncthreads();

    // S[128n][64m]: wave (wr,wc) covers n in wr*64.., m in wc*32..
    f32x4 sacc[4][2] = {};
#pragma unroll
    for (int ks = 0; ks < 4; ks++) {
      bf16x8 kf[2];
#pragma unroll
      for (int jm = 0; jm < 2; jm++)
        kf[jm] = *(const bf16x8*)&Ks[(wc * 32 + jm * 16 + fr) * 128 + ks * 32 + fk];
#pragma unroll
      for (int i = 0; i < 4; i++)
#pragma unroll
        for (int jm = 0; jm < 2; jm++) sacc[i][jm] = MFMA(qf[i][ks], kf[jm], sacc[i][jm]);
    }
    // silu + write P to LDS in [n][m] (A-operand friendly) layout
#pragma unroll
    for (int i = 0; i < 4; i++)
#pragma unroll
      for (int jm = 0; jm < 2; jm++)
#pragma unroll
        for (int r = 0; r < 4; r++) {
          float s = sacc[i][jm][r] * scale;
          float e = s / (1.f + __expf(-s));
          int n = wr * 64 + i * 16 + ((lane >> 4) << 2) + r;
          int m = wc * 32 + jm * 16 + (lane & 15);
          Ps[n * 64 + m] = (bf16)e;
        }
    __syncthreads();

    // O[128n][128dv] += P[128n][64m] @ V[64m][128dv]; wave: n wr*64.., dv wc*64..
#pragma unroll
    for (int ks = 0; ks < 2; ks++) {
      bf16x8 pf[4], vf[4];
#pragma unroll
      for (int i = 0; i < 4; i++)
        pf[i] = *(const bf16x8*)&Ps[(wr * 64 + i * 16 + fr) * 64 + ks * 32 + fk];
#pragma unroll
      for (int j = 0; j < 4; j++)
        vf[j] = *(const bf16x8*)&Vts[(wc * 64 + j * 16 + fr) * 64 + ks * 32 + fk];
#pragma unroll
      for (int i = 0; i < 4; i++)
#pragma unroll
        for (int j = 0; j < 4; j++) oacc[i][j] = MFMA(pf[i], vf[j], oacc[i][j]);
    }
  }

  bf16* obase = attn + (long)(b * NQ + nt * 128) * E + h * 128;
#pragma unroll
  for (int i = 0; i < 4; i++)
#pragma unroll
    for (int j = 0; j < 4; j++)
#pragma unroll
      for (int r = 0; r < 4; r++) {
        int n = wr * 64 + i * 16 + ((lane >> 4) << 2) + r;
        int dv = wc * 64 + j * 16 + (lane & 15);
        obase[(long)n * E + dv] = (bf16)(oacc[i][j][r] * scale);
      }
}

// ---------------------------------------------------------------------------
extern "C" void kernel_launch(void* const* d_in, const int* in_sizes, int n_in,
                              void* d_out, int out_size, void* d_ws, size_t ws_size,
                              hipStream_t stream) {
  const float* x = (const float*)d_in[0];     // [2,2048,2048] fp32
  const float* Wq = (const float*)d_in[1];    // [2048,2048]   fp32
  const float* kw = (const float*)d_in[2];    // [4096,2048]   fp32
  const float* vw = (const float*)d_in[3];    // [4096,2048]   fp32
  const float* Wg = (const float*)d_in[4];    // [2048,2048]   fp32
  const float* Wout = (const float*)d_in[5];  // [2048,2048]   fp32
  float* out = (float*)d_out;                 // [2,2048,2048] fp32
  bf16* ws = (bf16*)d_ws;

  // bf16 workspace layout (elements); total 88 MB
  bf16* xb = ws;                  // 8,388,608  [4096,2048]
  bf16* Wqb = ws + 8388608;       // 4,194,304  [2048,2048]  (reused for Wg)
  bf16* kwb = ws + 12582912;      // 8,388,608  [4096,2048]  (reused for Wout)
  bf16* vt = ws + 20971520;       // 8,388,608  [2048,4096]
  bf16* q = ws + 29360128;        // 8,388,608  [4096,2048]  (reused for gated)
  bf16* attn = ws + 37748736;     // 8,388,608  [4096,2048]

  // 0) fp32 -> bf16 conversions
  cvt_bf16<<<8192, 256, 0, stream>>>(x, xb, 8388608);
  cvt_bf16<<<4096, 256, 0, stream>>>(Wq, Wqb, 4194304);
  cvt_bf16<<<8192, 256, 0, stream>>>(kw, kwb, 8388608);
  transpose_v_cvt<<<dim3(64, 32), 256, 0, stream>>>(vw, vt);
  // 1) q = x @ Wq^T
  gemm_bt<0><<<dim3(16, 32), 256, 0, stream>>>(xb, Wqb, (const bf16*)nullptr, q, (float*)nullptr,
                                               4096, 2048, 2048);
  // 2) attn = scale * (silu(scale * q Kh^T) @ Vh), per head
  attn_fused<<<dim3(16, 32), 256, 0, stream>>>(q, kwb, vt, attn);
  // 3) gated = silu(x @ Wg^T) * attn   (Wg reuses Wq's bf16 slot; gated reuses q's)
  cvt_bf16<<<4096, 256, 0, stream>>>(Wg, Wqb, 4194304);
  gemm_bt<1><<<dim3(16, 32), 256, 0, stream>>>(xb, Wqb, attn, q, (float*)nullptr, 4096, 2048,
                                               2048);
  // 4) out = gated @ Wout^T (fp32 out; Wout reuses kw's bf16 slot)
  cvt_bf16<<<4096, 256, 0, stream>>>(Wout, kwb, 4194304);
  gemm_bt<2><<<dim3(16, 32), 256, 0, stream>>>(q, kwb, (const bf16*)nullptr, (bf16*)nullptr, out,
                                               4096, 2048, 2048);
}

// Round 3
// 541.835 us; speedup vs baseline: 1.0868x; 1.0868x over previous
//
#include <hip/hip_runtime.h>

typedef __bf16 bf16;
typedef __bf16 bf16x4 __attribute__((ext_vector_type(4)));
typedef __bf16 bf16x8 __attribute__((ext_vector_type(8)));
typedef float f32x4 __attribute__((ext_vector_type(4)));

#define MFMA(a, b, c) __builtin_amdgcn_mfma_f32_16x16x32_bf16(a, b, c, 0, 0, 0)

// async global->LDS, 16B per lane. HW constraint: LDS dest is wave-uniform
// base + lane*16 (contiguous). Swizzling therefore goes on the GLOBAL side.
__device__ __forceinline__ void gload_lds16(const void* g, void* l) {
  __builtin_amdgcn_global_load_lds(
      (const __attribute__((address_space(1))) void*)g,
      (__attribute__((address_space(3))) void*)l, 16, 0, 0);
}

// ---------------------------------------------------------------------------
// fp32 -> bf16 converter, 4 elems/thread.
// ---------------------------------------------------------------------------
__global__ __launch_bounds__(256) void cvt_bf16(const float* __restrict__ in,
                                                bf16* __restrict__ out, int n) {
  int i = (blockIdx.x * 256 + threadIdx.x) * 4;
  if (i >= n) return;
  float4 v = *(const float4*)(in + i);
  bf16x4 o = {(bf16)v.x, (bf16)v.y, (bf16)v.z, (bf16)v.w};
  *(bf16x4*)(out + i) = o;
}

// ---------------------------------------------------------------------------
// v_weight [4096,2048] fp32 -> vt [2048,4096] bf16 (vt[hd][m] = v[m][hd]).
// ---------------------------------------------------------------------------
__global__ __launch_bounds__(256) void transpose_v_cvt(const float* __restrict__ v,
                                                       bf16* __restrict__ vt) {
  __shared__ bf16 T[64 * 72];
  const int m0 = blockIdx.x * 64, c0 = blockIdx.y * 64;
  const int tid = threadIdx.x;
  const int tr = tid >> 3;        // 0..31
  const int tc = (tid & 7) << 3;  // 0,8,...,56
#pragma unroll
  for (int it = 0; it < 2; it++) {
    int r = tr + it * 32;
    const float* src = v + (long)(m0 + r) * 2048 + c0 + tc;
    float4 a = *(const float4*)src;
    float4 b = *(const float4*)(src + 4);
    bf16x8 t = {(bf16)a.x, (bf16)a.y, (bf16)a.z, (bf16)a.w,
                (bf16)b.x, (bf16)b.y, (bf16)b.z, (bf16)b.w};
    *(bf16x8*)&T[r * 72 + tc] = t;
  }
  __syncthreads();
#pragma unroll
  for (int it = 0; it < 2; it++) {
    int c = tr + it * 32;
    bf16x8 o;
#pragma unroll
    for (int j = 0; j < 8; j++) o[j] = T[(tc + j) * 72 + c];
    *(bf16x8*)(vt + (long)(c0 + c) * 4096 + m0 + tc) = o;
  }
}

// ---------------------------------------------------------------------------
// NT GEMM: C[M,N] = A[M,K] * B[N,K]^T, bf16 in, fp32 accum.
// MODE 0: C=result (bf16). MODE 1: C=silu(result)*other (bf16). MODE 2: fp32 out.
// 128x128 tile, BK=32, 256 threads (2x2 waves of 64x64).
// LDS tiles [128][32] (64B rows, 4x16B blocks), XOR-swizzled: blk ^= (row>>1)&3.
// ---------------------------------------------------------------------------
template <int MODE>
__global__ __launch_bounds__(256, 2) void gemm_bt(const bf16* __restrict__ A,
                                                  const bf16* __restrict__ B,
                                                  const bf16* __restrict__ other,
                                                  bf16* __restrict__ Cb,
                                                  float* __restrict__ Cf, int M, int N, int K) {
  __shared__ bf16 As[128 * 32];
  __shared__ bf16 Bs[128 * 32];
  const int tid = threadIdx.x;
  const int wave = tid >> 6, lane = tid & 63;
  const int wr = wave >> 1, wc = wave & 1;
  const long bM = (long)blockIdx.y * 128, bN = (long)blockIdx.x * 128;

  f32x4 acc[4][4] = {};

  // staging: wave w rows [w*32, w*32+32), 2 instrs of 16 rows each.
  // lane -> (row = w*32 + lane>>2, lds blk = lane&3); swizzle s(row)=(row>>1)&3
  // = (lane>>3)&3 for both instrs (row and row+16 share s).
  const int srow = (wave << 5) + (lane >> 2);
  const int sg = ((lane & 3) ^ ((lane >> 3) & 3)) << 3;  // global elem offset in row
  const bf16* Ag = A + (bM + srow) * (long)K + sg;
  const bf16* Bg = B + (bN + srow) * (long)K + sg;
  bf16* Asl = &As[srow * 32 + ((lane & 3) << 3)];
  bf16* Bsl = &Bs[srow * 32 + ((lane & 3) << 3)];

  const int fr = lane & 15;                              // fragment row
  const int gofs = (((lane >> 4) ^ ((fr >> 1) & 3)) << 3);  // swizzled frag col

  for (int k0 = 0; k0 < K; k0 += 32) {
    __syncthreads();
    gload_lds16(Ag + k0, Asl);
    gload_lds16(Ag + k0 + (long)16 * K, Asl + 16 * 32);
    gload_lds16(Bg + k0, Bsl);
    gload_lds16(Bg + k0 + (long)16 * K, Bsl + 16 * 32);
    __syncthreads();
    bf16x8 af[4], bfv[4];
#pragma unroll
    for (int i = 0; i < 4; i++)
      af[i] = *(const bf16x8*)&As[(wr * 64 + i * 16 + fr) * 32 + gofs];
#pragma unroll
    for (int j = 0; j < 4; j++)
      bfv[j] = *(const bf16x8*)&Bs[(wc * 64 + j * 16 + fr) * 32 + gofs];
#pragma unroll
    for (int i = 0; i < 4; i++)
#pragma unroll
      for (int j = 0; j < 4; j++) acc[i][j] = MFMA(af[i], bfv[j], acc[i][j]);
  }

  const int er = wr * 64 + ((lane >> 4) << 2);
  const int ec = wc * 64 + (lane & 15);
#pragma unroll
  for (int i = 0; i < 4; i++)
#pragma unroll
    for (int j = 0; j < 4; j++)
#pragma unroll
      for (int r = 0; r < 4; r++) {
        long row = bM + er + i * 16 + r;
        long col = bN + ec + j * 16;
        float v = acc[i][j][r];
        if (MODE == 1) {
          float g = v / (1.f + __expf(-v));  // silu
          v = g * (float)other[row * (long)N + col];
        }
        if (MODE == 2)
          Cf[row * (long)N + col] = v;
        else
          Cb[row * (long)N + col] = (bf16)v;
      }
}

// ---------------------------------------------------------------------------
// Fused attention: per (b,h,ntile): O = scale*(silu(scale*Q Kh^T) @ Vh),
// streamed over M in 64-chunks. Q frags in registers. P via LDS round-trip.
// All LDS tiles XOR-swizzled at 16B granularity:
//   Ks [64][128]: 16 blks/row, blk ^= row&15
//   Vts[128][64]:  8 blks/row, blk ^= row&7
//   Ps [128][64]:  8 blks/row, blk ^= row&7
// Grid: flat 512, XCD-grouped (2 heads per XCD -> 4MB K/V fits per-XCD L2).
// ---------------------------------------------------------------------------
__global__ __launch_bounds__(256, 2) void attn_fused(const bf16* __restrict__ q,
                                                     const bf16* __restrict__ kw,
                                                     const bf16* __restrict__ vt,
                                                     bf16* __restrict__ attn) {
  constexpr int E = 2048, M = 4096, NQ = 2048;
  constexpr float scale = 11.3137085f;  // sqrt(dk)=sqrt(128)
  // XCD-aware decode: h = xcd*2 + (l>>5); blocks sharing h land on one XCD
  const int bid = blockIdx.x;
  const int h = ((bid & 7) << 1) | ((bid >> 8) & 1);
  const int sub = (bid >> 3) & 31;
  const int b = sub >> 4, nt = sub & 15;

  const int tid = threadIdx.x, wave = tid >> 6, lane = tid & 63;
  const int wr = wave >> 1, wc = wave & 1;
  const int fr = lane & 15, fk = (lane >> 4) << 3;
  const int quad = lane >> 4;

  __shared__ bf16 Ks[64 * 128];   // [m][d]   16KB
  __shared__ bf16 Vts[128 * 64];  // [dv][m]  16KB
  __shared__ bf16 Ps[128 * 64];   // [n][m]   16KB

  // Q fragments: wave's 64 n-rows x dk=128, loaded once (global, no swizzle)
  const bf16* qbase = q + (long)(b * NQ + nt * 128) * E + h * 128;
  bf16x8 qf[4][4];
#pragma unroll
  for (int i = 0; i < 4; i++)
#pragma unroll
    for (int ks = 0; ks < 4; ks++)
      qf[i][ks] = *(const bf16x8*)(qbase + (long)(wr * 64 + i * 16 + fr) * E + ks * 32 + fk);

  f32x4 oacc[4][4] = {};

  // K staging: wave w rows [w*16,w*16+16) over 4 instrs of 4 rows.
  // lane -> (row_in_instr = quad, lds blk = lane&15); s(row) = (quad+4i)&15.
  const int krow = (wave << 4) + quad;
  bf16* ksl = &Ks[krow * 128 + ((lane & 15) << 3)];
  const bf16* kg = kw + (long)krow * E + h * 128;  // + swizzled col per instr

  // V staging: wave w rows [w*32,w*32+32) over 4 instrs of 8 rows.
  // lane -> (row = w*32 + lane>>3, lds blk = lane&7); s = (lane>>3)&7 (all i).
  const int vrow = (wave << 5) + (lane >> 3);
  const int vg_ofs = ((lane & 7) ^ ((lane >> 3) & 7)) << 3;
  const bf16* vg = vt + (long)(h * 128 + vrow) * M + vg_ofs;
  bf16* vsl = &Vts[vrow * 64 + ((lane & 7) << 3)];

  for (int m0 = 0; m0 < M; m0 += 64) {
    __syncthreads();
#pragma unroll
    for (int i = 0; i < 4; i++) {
      int kswz = ((lane & 15) ^ ((quad + 4 * i) & 15)) << 3;
      gload_lds16(kg + (long)(m0 + i * 4) * E + kswz, ksl + i * 4 * 128);
      gload_lds16(vg + m0 + (long)i * 8 * M, vsl + i * 8 * 64);
    }
    __syncthreads();

    // S[128n][64m]: wave (wr,wc): n in wr*64.., m in wc*32..
    f32x4 sacc[4][2] = {};
#pragma unroll
    for (int ks = 0; ks < 4; ks++) {
      bf16x8 kf[2];
#pragma unroll
      for (int jm = 0; jm < 2; jm++)
        kf[jm] = *(const bf16x8*)&Ks[(wc * 32 + jm * 16 + fr) * 128 +
                                     (((ks * 4 + quad) ^ fr) << 3)];
#pragma unroll
      for (int i = 0; i < 4; i++)
#pragma unroll
        for (int jm = 0; jm < 2; jm++) sacc[i][jm] = MFMA(qf[i][ks], kf[jm], sacc[i][jm]);
    }
    // silu + write P to LDS ([n][m], swizzled)
#pragma unroll
    for (int i = 0; i < 4; i++)
#pragma unroll
      for (int jm = 0; jm < 2; jm++)
#pragma unroll
        for (int r = 0; r < 4; r++) {
          float s = sacc[i][jm][r] * scale;
          float e = s / (1.f + __expf(-s));
          int n = wr * 64 + i * 16 + quad * 4 + r;
          int m = wc * 32 + jm * 16 + (lane & 15);
          Ps[n * 64 + (((m >> 3) ^ (n & 7)) << 3) + (m & 7)] = (bf16)e;
        }
    __syncthreads();

    // O[128n][128dv] += P @ V; wave: n wr*64.., dv wc*64..
#pragma unroll
    for (int ks = 0; ks < 2; ks++) {
      const int pvo = (((ks * 4 + quad) ^ (fr & 7)) << 3);
      bf16x8 pf[4], vf[4];
#pragma unroll
      for (int i = 0; i < 4; i++)
        pf[i] = *(const bf16x8*)&Ps[(wr * 64 + i * 16 + fr) * 64 + pvo];
#pragma unroll
      for (int j = 0; j < 4; j++)
        vf[j] = *(const bf16x8*)&Vts[(wc * 64 + j * 16 + fr) * 64 + pvo];
#pragma unroll
      for (int i = 0; i < 4; i++)
#pragma unroll
        for (int j = 0; j < 4; j++) oacc[i][j] = MFMA(pf[i], vf[j], oacc[i][j]);
    }
  }

  bf16* obase = attn + (long)(b * NQ + nt * 128) * E + h * 128;
#pragma unroll
  for (int i = 0; i < 4; i++)
#pragma unroll
    for (int j = 0; j < 4; j++)
#pragma unroll
      for (int r = 0; r < 4; r++) {
        int n = wr * 64 + i * 16 + quad * 4 + r;
        int dv = wc * 64 + j * 16 + (lane & 15);
        obase[(long)n * E + dv] = (bf16)(oacc[i][j][r] * scale);
      }
}

// ---------------------------------------------------------------------------
extern "C" void kernel_launch(void* const* d_in, const int* in_sizes, int n_in,
                              void* d_out, int out_size, void* d_ws, size_t ws_size,
                              hipStream_t stream) {
  const float* x = (const float*)d_in[0];     // [2,2048,2048] fp32
  const float* Wq = (const float*)d_in[1];    // [2048,2048]   fp32
  const float* kw = (const float*)d_in[2];    // [4096,2048]   fp32
  const float* vw = (const float*)d_in[3];    // [4096,2048]   fp32
  const float* Wg = (const float*)d_in[4];    // [2048,2048]   fp32
  const float* Wout = (const float*)d_in[5];  // [2048,2048]   fp32
  float* out = (float*)d_out;                 // [2,2048,2048] fp32
  bf16* ws = (bf16*)d_ws;

  bf16* xb = ws;                  // 8,388,608  [4096,2048]
  bf16* Wqb = ws + 8388608;       // 4,194,304  (reused for Wg)
  bf16* kwb = ws + 12582912;      // 8,388,608  (reused for Wout)
  bf16* vt = ws + 20971520;       // 8,388,608  [2048,4096]
  bf16* q = ws + 29360128;        // 8,388,608  (reused for gated)
  bf16* attn = ws + 37748736;     // 8,388,608

  cvt_bf16<<<8192, 256, 0, stream>>>(x, xb, 8388608);
  cvt_bf16<<<4096, 256, 0, stream>>>(Wq, Wqb, 4194304);
  cvt_bf16<<<8192, 256, 0, stream>>>(kw, kwb, 8388608);
  transpose_v_cvt<<<dim3(64, 32), 256, 0, stream>>>(vw, vt);
  // 1) q = x @ Wq^T
  gemm_bt<0><<<dim3(16, 32), 256, 0, stream>>>(xb, Wqb, (const bf16*)nullptr, q, (float*)nullptr,
                                               4096, 2048, 2048);
  // 2) attn
  attn_fused<<<512, 256, 0, stream>>>(q, kwb, vt, attn);
  // 3) gated = silu(x @ Wg^T) * attn
  cvt_bf16<<<4096, 256, 0, stream>>>(Wg, Wqb, 4194304);
  gemm_bt<1><<<dim3(16, 32), 256, 0, stream>>>(xb, Wqb, attn, q, (float*)nullptr, 4096, 2048,
                                               2048);
  // 4) out = gated @ Wout^T
  cvt_bf16<<<4096, 256, 0, stream>>>(Wout, kwb, 4194304);
  gemm_bt<2><<<dim3(16, 32), 256, 0, stream>>>(q, kwb, (const bf16*)nullptr, (bf16*)nullptr, out,
                                               4096, 2048, 2048);
}

// Round 4
// 481.388 us; speedup vs baseline: 1.2233x; 1.1256x over previous
//
#include <hip/hip_runtime.h>

typedef __bf16 bf16;
typedef __bf16 bf16x4 __attribute__((ext_vector_type(4)));
typedef __bf16 bf16x8 __attribute__((ext_vector_type(8)));
typedef float f32x4 __attribute__((ext_vector_type(4)));

#define MFMA(a, b, c) __builtin_amdgcn_mfma_f32_16x16x32_bf16(a, b, c, 0, 0, 0)

__device__ __forceinline__ float fast_silu(float x) {
  // x * sigmoid(x), division-free: v_mul, v_exp, v_add, v_rcp, v_mul
  float e = __builtin_amdgcn_exp2f(x * -1.4426950408889634f);
  return x * __builtin_amdgcn_rcpf(1.f + e);
}

// async global->LDS, 16B/lane. LDS dest must be wave-uniform base + lane*16;
// all swizzling goes on the GLOBAL address.
__device__ __forceinline__ void gload_lds16(const void* g, void* l) {
  __builtin_amdgcn_global_load_lds(
      (const __attribute__((address_space(1))) void*)g,
      (__attribute__((address_space(3))) void*)l, 16, 0, 0);
}

// ---------------------------------------------------------------------------
__global__ __launch_bounds__(256) void cvt_bf16(const float* __restrict__ in,
                                                bf16* __restrict__ out, int n) {
  int i = (blockIdx.x * 256 + threadIdx.x) * 4;
  if (i >= n) return;
  float4 v = *(const float4*)(in + i);
  bf16x4 o = {(bf16)v.x, (bf16)v.y, (bf16)v.z, (bf16)v.w};
  *(bf16x4*)(out + i) = o;
}

// v_weight [4096,2048] fp32 -> vt [2048,4096] bf16 (vt[hd][m] = v[m][hd]).
__global__ __launch_bounds__(256) void transpose_v_cvt(const float* __restrict__ v,
                                                       bf16* __restrict__ vt) {
  __shared__ bf16 T[64 * 72];
  const int m0 = blockIdx.x * 64, c0 = blockIdx.y * 64;
  const int tid = threadIdx.x;
  const int tr = tid >> 3;        // 0..31
  const int tc = (tid & 7) << 3;  // 0..56
#pragma unroll
  for (int it = 0; it < 2; it++) {
    int r = tr + it * 32;
    const float* src = v + (long)(m0 + r) * 2048 + c0 + tc;
    float4 a = *(const float4*)src;
    float4 b = *(const float4*)(src + 4);
    bf16x8 t = {(bf16)a.x, (bf16)a.y, (bf16)a.z, (bf16)a.w,
                (bf16)b.x, (bf16)b.y, (bf16)b.z, (bf16)b.w};
    *(bf16x8*)&T[r * 72 + tc] = t;
  }
  __syncthreads();
#pragma unroll
  for (int it = 0; it < 2; it++) {
    int c = tr + it * 32;
    bf16x8 o;
#pragma unroll
    for (int j = 0; j < 8; j++) o[j] = T[(tc + j) * 72 + c];
    *(bf16x8*)(vt + (long)(c0 + c) * 4096 + m0 + tc) = o;
  }
}

// ---------------------------------------------------------------------------
// NT GEMM, 128x128 tile, BK=32. MODE 2: C = result (fp32 out).
// MODE 3: dual-output: blockIdx.x<16 -> C1 = qscale*(A B^T); else
//         C2 = silu(A B2^T), col base (blockIdx.x-16)*128. N=2048 addressing.
// LDS swizzled blk ^= (row>>1)&3 (16B blocks, 4/row).
// ---------------------------------------------------------------------------
template <int MODE>
__global__ __launch_bounds__(256, 2) void gemm_bt(const bf16* __restrict__ A,
                                                  const bf16* __restrict__ B,
                                                  const bf16* __restrict__ B2,
                                                  bf16* __restrict__ C1,
                                                  bf16* __restrict__ C2,
                                                  float* __restrict__ Cf, int M, int N, int K) {
  __shared__ bf16 As[128 * 32];
  __shared__ bf16 Bs[128 * 32];
  const int tid = threadIdx.x;
  const int wave = tid >> 6, lane = tid & 63;
  const int wr = wave >> 1, wc = wave & 1;
  const bool gsel = (MODE == 3) && (blockIdx.x >= 16);
  const bf16* Bm = gsel ? B2 : B;
  const long bM = (long)blockIdx.y * 128;
  const long bN = (long)((MODE == 3) ? (blockIdx.x & 15) : blockIdx.x) * 128;

  f32x4 acc[4][4] = {};

  const int srow = (wave << 5) + (lane >> 2);
  const int sg = ((lane & 3) ^ ((lane >> 3) & 3)) << 3;
  const bf16* Ag = A + (bM + srow) * (long)K + sg;
  const bf16* Bg = Bm + (bN + srow) * (long)K + sg;
  bf16* Asl = &As[srow * 32 + ((lane & 3) << 3)];
  bf16* Bsl = &Bs[srow * 32 + ((lane & 3) << 3)];

  const int fr = lane & 15;
  const int gofs = (((lane >> 4) ^ ((fr >> 1) & 3)) << 3);

  for (int k0 = 0; k0 < K; k0 += 32) {
    __syncthreads();
    gload_lds16(Ag + k0, Asl);
    gload_lds16(Ag + k0 + (long)16 * K, Asl + 16 * 32);
    gload_lds16(Bg + k0, Bsl);
    gload_lds16(Bg + k0 + (long)16 * K, Bsl + 16 * 32);
    __syncthreads();
    bf16x8 af[4], bfv[4];
#pragma unroll
    for (int i = 0; i < 4; i++)
      af[i] = *(const bf16x8*)&As[(wr * 64 + i * 16 + fr) * 32 + gofs];
#pragma unroll
    for (int j = 0; j < 4; j++)
      bfv[j] = *(const bf16x8*)&Bs[(wc * 64 + j * 16 + fr) * 32 + gofs];
#pragma unroll
    for (int i = 0; i < 4; i++)
#pragma unroll
      for (int j = 0; j < 4; j++) acc[i][j] = MFMA(af[i], bfv[j], acc[i][j]);
  }

  const int er = wr * 64 + ((lane >> 4) << 2);
  const int ec = wc * 64 + (lane & 15);
#pragma unroll
  for (int i = 0; i < 4; i++)
#pragma unroll
    for (int j = 0; j < 4; j++)
#pragma unroll
      for (int r = 0; r < 4; r++) {
        long row = bM + er + i * 16 + r;
        long col = bN + ec + j * 16;
        float v = acc[i][j][r];
        if (MODE == 2) {
          Cf[row * (long)N + col] = v;
        } else {  // MODE 3
          if (gsel)
            C2[row * (long)N + col] = (bf16)fast_silu(v);
          else
            C1[row * (long)N + col] = (bf16)(v * 11.3137085f);  // sqrt(dk)
        }
      }
}

// ---------------------------------------------------------------------------
// Fused attention, S^T formulation. Per block: 64 Q-rows, one head.
//   S^T[m][n] = K[m][:]·q_scaled[n][:]   (K from LDS as A, Q in regs as B)
//   P = silu(S^T) packed from C-layout regs -> Ps[n][m] via ds_write_b64
//   O[n][dv] += P[n][:]·V^T[dv][:]       (P, V^T from LDS, K=32 MFMA)
// Epilogue: gated[n][dv] = gate[n][dv] * O * scale  (gate = pre-silu'd glin)
// LDS: Ks 16KB + Vts 16KB + Ps 8KB = 40KB -> 4 blocks/CU.
// Swizzles (16B blocks): Ks blk^=m&15, Vts blk^=dv&7, Ps blk^=n&7.
// Grid 1024 flat, XCD-grouped: 2 heads/XCD -> 4MB K/V per XCD L2.
// ---------------------------------------------------------------------------
__global__ __launch_bounds__(256, 4) void attn_fused(const bf16* __restrict__ q,
                                                     const bf16* __restrict__ kw,
                                                     const bf16* __restrict__ vt,
                                                     bf16* __restrict__ gate_io) {
  constexpr int E = 2048, M = 4096;
  constexpr float scale = 11.3137085f;  // sqrt(dv) folded out of V
  const int bid = blockIdx.x;
  const int h = ((bid & 7) << 1) | ((bid >> 9) & 1);
  const int b = (bid >> 8) & 1;
  const int nt = (bid >> 3) & 31;
  const long n0 = (long)b * 2048 + nt * 64;

  const int tid = threadIdx.x, wave = tid >> 6, lane = tid & 63;
  const int quad = lane >> 4, ln = lane & 15;
  const int sw_m = wave & 1, sw_n = wave >> 1;  // S^T split: m 32, n 32
  const int pw_n = wave & 1, pw_dv = wave >> 1; // PV split:  n 32, dv 64

  __shared__ bf16 Ks[64 * 128];
  __shared__ bf16 Vts[128 * 64];
  __shared__ bf16 Ps[64 * 64];

  // Q B-fragments (pre-scaled by sqrt(dk) in the producing GEMM)
  const bf16* qbase = q + (n0 + sw_n * 32) * E + h * 128;
  bf16x8 qf[2][4];
#pragma unroll
  for (int t = 0; t < 2; t++)
#pragma unroll
    for (int ks = 0; ks < 4; ks++)
      qf[t][ks] = *(const bf16x8*)(qbase + (long)(t * 16 + ln) * E + ks * 32 + (quad << 3));

  f32x4 oacc[2][4] = {};

  // K staging: wave rows [wave*16,+16), 4 instrs of 4 rows
  const bf16* kg = kw + (long)((wave << 4) + quad) * E + h * 128;
  bf16* ksl = &Ks[(wave << 4) * 128 + lane * 8];
  int kc[4];
#pragma unroll
  for (int i = 0; i < 4; i++) kc[i] = (ln ^ ((quad + i * 4) & 15)) << 3;

  // V staging: wave dv-rows [wave*32,+32), 4 instrs of 8 rows
  const bf16* vg = vt + (long)(h * 128 + (wave << 5) + (lane >> 3)) * M +
                   (((lane & 7) ^ ((lane >> 3) & 7)) << 3);
  bf16* vsl = &Vts[(wave << 5) * 64 + lane * 8];

  // P-write addresses (4, hoisted): tile (mt,nt2)
  int waddr[2][2];
#pragma unroll
  for (int mt = 0; mt < 2; mt++)
#pragma unroll
    for (int n2 = 0; n2 < 2; n2++) {
      int n = sw_n * 32 + n2 * 16 + ln;
      int mb8 = sw_m * 4 + mt * 2 + (quad >> 1);
      waddr[mt][n2] = n * 64 + ((mb8 ^ (n & 7)) << 3) + ((quad & 1) << 2);
    }

  for (int m0 = 0; m0 < M; m0 += 64) {
    __syncthreads();
#pragma unroll
    for (int i = 0; i < 4; i++) {
      gload_lds16(kg + (long)(m0 + i * 4) * E + kc[i], ksl + i * 4 * 128);
      gload_lds16(vg + m0 + (long)i * 8 * M, vsl + i * 8 * 64);
    }
    __syncthreads();

    // S^T = K · Q^T  (D rows = m, cols = n)
    f32x4 sacc[2][2] = {};
#pragma unroll
    for (int ks = 0; ks < 4; ks++) {
      bf16x8 af[2];
#pragma unroll
      for (int mt = 0; mt < 2; mt++)
        af[mt] = *(const bf16x8*)&Ks[(sw_m * 32 + mt * 16 + ln) * 128 +
                                     (((ks * 4 + quad) ^ ln) << 3)];
#pragma unroll
      for (int mt = 0; mt < 2; mt++)
#pragma unroll
        for (int n2 = 0; n2 < 2; n2++) sacc[mt][n2] = MFMA(af[mt], qf[n2][ks], sacc[mt][n2]);
    }

    // silu + pack 4 m-consecutive values -> one ds_write_b64 per tile
#pragma unroll
    for (int mt = 0; mt < 2; mt++)
#pragma unroll
      for (int n2 = 0; n2 < 2; n2++) {
        bf16x4 p;
#pragma unroll
        for (int r = 0; r < 4; r++) p[r] = (bf16)fast_silu(sacc[mt][n2][r]);
        *(bf16x4*)&Ps[waddr[mt][n2]] = p;
      }
    __syncthreads();

    // O += P · V^T
#pragma unroll
    for (int ks = 0; ks < 2; ks++) {
      const int so = ((ks * 4 + quad) ^ (ln & 7)) << 3;
      bf16x8 pf[2], vf[4];
#pragma unroll
      for (int n2 = 0; n2 < 2; n2++)
        pf[n2] = *(const bf16x8*)&Ps[(pw_n * 32 + n2 * 16 + ln) * 64 + so];
#pragma unroll
      for (int dt = 0; dt < 4; dt++)
        vf[dt] = *(const bf16x8*)&Vts[(pw_dv * 64 + dt * 16 + ln) * 64 + so];
#pragma unroll
      for (int n2 = 0; n2 < 2; n2++)
#pragma unroll
        for (int dt = 0; dt < 4; dt++) oacc[n2][dt] = MFMA(pf[n2], vf[dt], oacc[n2][dt]);
    }
  }

  // Epilogue: gated = gate * (O * scale); gate_io aliases glin/gated (same elems)
  bf16* gio = gate_io + n0 * E + h * 128;
#pragma unroll
  for (int n2 = 0; n2 < 2; n2++)
#pragma unroll
    for (int dt = 0; dt < 4; dt++)
#pragma unroll
      for (int r = 0; r < 4; r++) {
        int n = pw_n * 32 + n2 * 16 + quad * 4 + r;
        int dv = pw_dv * 64 + dt * 16 + ln;
        float g = (float)gio[(long)n * E + dv];
        gio[(long)n * E + dv] = (bf16)(g * oacc[n2][dt][r] * scale);
      }
}

// ---------------------------------------------------------------------------
extern "C" void kernel_launch(void* const* d_in, const int* in_sizes, int n_in,
                              void* d_out, int out_size, void* d_ws, size_t ws_size,
                              hipStream_t stream) {
  const float* x = (const float*)d_in[0];
  const float* Wq = (const float*)d_in[1];
  const float* kw = (const float*)d_in[2];
  const float* vw = (const float*)d_in[3];
  const float* Wg = (const float*)d_in[4];
  const float* Wout = (const float*)d_in[5];
  float* out = (float*)d_out;
  bf16* ws = (bf16*)d_ws;

  // 5 slots x 8,388,608 bf16 = 83.9 MB
  bf16* S0 = ws;              // xb, then kwb
  bf16* S1 = ws + 8388608;    // Wqb | Wgb, then Woutb
  bf16* S2 = ws + 16777216;   // vt
  bf16* S3 = ws + 25165824;   // q (pre-scaled)
  bf16* S4 = ws + 33554432;   // glin (silu'd) -> gated in-place
  bf16* Wgb = S1 + 4194304;

  cvt_bf16<<<8192, 256, 0, stream>>>(x, S0, 8388608);
  cvt_bf16<<<4096, 256, 0, stream>>>(Wq, S1, 4194304);
  cvt_bf16<<<4096, 256, 0, stream>>>(Wg, Wgb, 4194304);
  transpose_v_cvt<<<dim3(64, 32), 256, 0, stream>>>(vw, S2);
  // q = qscale*(x Wq^T); glin = silu(x Wg^T)  — one dual GEMM, 1024 blocks
  gemm_bt<3><<<dim3(32, 32), 256, 0, stream>>>(S0, S1, Wgb, S3, S4, (float*)nullptr, 4096, 2048,
                                               2048);
  cvt_bf16<<<8192, 256, 0, stream>>>(kw, S0, 8388608);  // xb dead -> kwb
  // gated = glin * scale * (silu(q K^T) V), in-place on S4
  attn_fused<<<1024, 256, 0, stream>>>(S3, S0, S2, S4);
  cvt_bf16<<<4096, 256, 0, stream>>>(Wout, S1, 4194304);  // Wq/Wg dead -> Woutb
  // out = gated Wout^T (fp32)
  gemm_bt<2><<<dim3(16, 32), 256, 0, stream>>>(S4, S1, (const bf16*)nullptr, (bf16*)nullptr,
                                               (bf16*)nullptr, out, 4096, 2048, 2048);
}

// Round 5
// 478.369 us; speedup vs baseline: 1.2310x; 1.0063x over previous
//
#include <hip/hip_runtime.h>

typedef __bf16 bf16;
typedef __bf16 bf16x4 __attribute__((ext_vector_type(4)));
typedef __bf16 bf16x8 __attribute__((ext_vector_type(8)));
typedef float f32x4 __attribute__((ext_vector_type(4)));

#define MFMA(a, b, c) __builtin_amdgcn_mfma_f32_16x16x32_bf16(a, b, c, 0, 0, 0)

__device__ __forceinline__ float fast_silu(float x) {
  float e = __builtin_amdgcn_exp2f(x * -1.4426950408889634f);
  return x * __builtin_amdgcn_rcpf(1.f + e);
}

// async global->LDS, 16B/lane. LDS dest must be wave-uniform base + lane*16;
// all swizzling goes on the GLOBAL address.
__device__ __forceinline__ void gload_lds16(const void* g, void* l) {
  __builtin_amdgcn_global_load_lds(
      (const __attribute__((address_space(1))) void*)g,
      (__attribute__((address_space(3))) void*)l, 16, 0, 0);
}

// ---------------------------------------------------------------------------
__global__ __launch_bounds__(256) void cvt_bf16(const float* __restrict__ in,
                                                bf16* __restrict__ out, int n) {
  int i = (blockIdx.x * 256 + threadIdx.x) * 4;
  if (i >= n) return;
  float4 v = *(const float4*)(in + i);
  bf16x4 o = {(bf16)v.x, (bf16)v.y, (bf16)v.z, (bf16)v.w};
  *(bf16x4*)(out + i) = o;
}

// v_weight [4096,2048] fp32 -> vt [2048,4096] bf16 (vt[hd][m] = v[m][hd]).
__global__ __launch_bounds__(256) void transpose_v_cvt(const float* __restrict__ v,
                                                       bf16* __restrict__ vt) {
  __shared__ bf16 T[64 * 72];
  const int m0 = blockIdx.x * 64, c0 = blockIdx.y * 64;
  const int tid = threadIdx.x;
  const int tr = tid >> 3;        // 0..31
  const int tc = (tid & 7) << 3;  // 0..56
#pragma unroll
  for (int it = 0; it < 2; it++) {
    int r = tr + it * 32;
    const float* src = v + (long)(m0 + r) * 2048 + c0 + tc;
    float4 a = *(const float4*)src;
    float4 b = *(const float4*)(src + 4);
    bf16x8 t = {(bf16)a.x, (bf16)a.y, (bf16)a.z, (bf16)a.w,
                (bf16)b.x, (bf16)b.y, (bf16)b.z, (bf16)b.w};
    *(bf16x8*)&T[r * 72 + tc] = t;
  }
  __syncthreads();
#pragma unroll
  for (int it = 0; it < 2; it++) {
    int c = tr + it * 32;
    bf16x8 o;
#pragma unroll
    for (int j = 0; j < 8; j++) o[j] = T[(tc + j) * 72 + c];
    *(bf16x8*)(vt + (long)(c0 + c) * 4096 + m0 + tc) = o;
  }
}

// ---------------------------------------------------------------------------
// NT GEMM, 128x128 tile, BK=32. MODE 2: C = result (fp32 out).
// MODE 3: dual-output: blockIdx.x<16 -> C1 = qscale*(A B^T); else
//         C2 = silu(A B2^T). LDS swizzled blk ^= (row>>1)&3.
// ---------------------------------------------------------------------------
template <int MODE>
__global__ __launch_bounds__(256, 2) void gemm_bt(const bf16* __restrict__ A,
                                                  const bf16* __restrict__ B,
                                                  const bf16* __restrict__ B2,
                                                  bf16* __restrict__ C1,
                                                  bf16* __restrict__ C2,
                                                  float* __restrict__ Cf, int M, int N, int K) {
  __shared__ bf16 As[128 * 32];
  __shared__ bf16 Bs[128 * 32];
  const int tid = threadIdx.x;
  const int wave = tid >> 6, lane = tid & 63;
  const int wr = wave >> 1, wc = wave & 1;
  const bool gsel = (MODE == 3) && (blockIdx.x >= 16);
  const bf16* Bm = gsel ? B2 : B;
  const long bM = (long)blockIdx.y * 128;
  const long bN = (long)((MODE == 3) ? (blockIdx.x & 15) : blockIdx.x) * 128;

  f32x4 acc[4][4] = {};

  const int srow = (wave << 5) + (lane >> 2);
  const int sg = ((lane & 3) ^ ((lane >> 3) & 3)) << 3;
  const bf16* Ag = A + (bM + srow) * (long)K + sg;
  const bf16* Bg = Bm + (bN + srow) * (long)K + sg;
  bf16* Asl = &As[srow * 32 + ((lane & 3) << 3)];
  bf16* Bsl = &Bs[srow * 32 + ((lane & 3) << 3)];

  const int fr = lane & 15;
  const int gofs = (((lane >> 4) ^ ((fr >> 1) & 3)) << 3);

  for (int k0 = 0; k0 < K; k0 += 32) {
    __syncthreads();
    gload_lds16(Ag + k0, Asl);
    gload_lds16(Ag + k0 + (long)16 * K, Asl + 16 * 32);
    gload_lds16(Bg + k0, Bsl);
    gload_lds16(Bg + k0 + (long)16 * K, Bsl + 16 * 32);
    __syncthreads();
    bf16x8 af[4], bfv[4];
#pragma unroll
    for (int i = 0; i < 4; i++)
      af[i] = *(const bf16x8*)&As[(wr * 64 + i * 16 + fr) * 32 + gofs];
#pragma unroll
    for (int j = 0; j < 4; j++)
      bfv[j] = *(const bf16x8*)&Bs[(wc * 64 + j * 16 + fr) * 32 + gofs];
#pragma unroll
    for (int i = 0; i < 4; i++)
#pragma unroll
      for (int j = 0; j < 4; j++) acc[i][j] = MFMA(af[i], bfv[j], acc[i][j]);
  }

  const int er = wr * 64 + ((lane >> 4) << 2);
  const int ec = wc * 64 + (lane & 15);
#pragma unroll
  for (int i = 0; i < 4; i++)
#pragma unroll
    for (int j = 0; j < 4; j++)
#pragma unroll
      for (int r = 0; r < 4; r++) {
        long row = bM + er + i * 16 + r;
        long col = bN + ec + j * 16;
        float v = acc[i][j][r];
        if (MODE == 2) {
          Cf[row * (long)N + col] = v;
        } else {  // MODE 3
          if (gsel)
            C2[row * (long)N + col] = (bf16)fast_silu(v);
          else
            C1[row * (long)N + col] = (bf16)(v * 11.3137085f);  // sqrt(dk)
        }
      }
}

// ---------------------------------------------------------------------------
// Fused attention, S^T formulation, 128 Q-rows per block.
//   S^T[m64][n128] = K·q^T  (K from LDS as A, Q in regs as B; wave m32 x n64)
//   P = silu(S^T) packed (4 m-consecutive) -> Ps[n][m] via ds_write_b64
//   O[n128][dv128] += P·V^T (wave n64 x dv64, K=32 MFMA)
// Epilogue: gated = gate * O * scale (gate = pre-silu'd glin, in-place RMW).
// LDS: Ks[64][128] 16KB + Vts[128][64] 16KB + Ps[128][64] 16KB = 48KB.
// Swizzles (16B blocks): Ks blk^=m&15, Vts blk^=dv&7, Ps blk^=n&7.
// Grid 512 flat, XCD-grouped (2 heads/XCD -> K/V in per-XCD L2).
// ---------------------------------------------------------------------------
__global__ __launch_bounds__(256, 2) void attn_fused(const bf16* __restrict__ q,
                                                     const bf16* __restrict__ kw,
                                                     const bf16* __restrict__ vt,
                                                     bf16* __restrict__ gate_io) {
  constexpr int E = 2048, M = 4096;
  constexpr float scale = 11.3137085f;  // sqrt(dv) folded out of V
  const int bid = blockIdx.x;
  const int h = ((bid & 7) << 1) | ((bid >> 8) & 1);
  const int sub = (bid >> 3) & 31;
  const int b = sub >> 4, nt = sub & 15;
  const long n0 = (long)b * 2048 + nt * 128;

  const int tid = threadIdx.x, wave = tid >> 6, lane = tid & 63;
  const int quad = lane >> 4, ln = lane & 15;
  const int sw_m = wave & 1, sw_n = wave >> 1;   // S^T: wave tile m32 x n64
  const int pw_n = wave & 1, pw_dv = wave >> 1;  // PV:  wave tile n64 x dv64

  __shared__ bf16 Ks[64 * 128];
  __shared__ bf16 Vts[128 * 64];
  __shared__ bf16 Ps[128 * 64];

  // Q B-fragments: n64 x dk128 per wave (pre-scaled by sqrt(dk))
  const bf16* qbase = q + (n0 + sw_n * 64) * E + h * 128;
  bf16x8 qf[4][4];
#pragma unroll
  for (int n2 = 0; n2 < 4; n2++)
#pragma unroll
    for (int ks = 0; ks < 4; ks++)
      qf[n2][ks] = *(const bf16x8*)(qbase + (long)(n2 * 16 + ln) * E + ks * 32 + (quad << 3));

  f32x4 oacc[4][4] = {};

  // K staging: wave rows [wave*16,+16), 4 instrs of 4 rows
  const bf16* kg = kw + (long)((wave << 4) + quad) * E + h * 128;
  bf16* ksl = &Ks[(wave << 4) * 128 + lane * 8];
  int kc[4];
#pragma unroll
  for (int i = 0; i < 4; i++) kc[i] = (ln ^ ((quad + i * 4) & 15)) << 3;

  // V staging: wave dv-rows [wave*32,+32), 4 instrs of 8 rows
  const bf16* vg = vt + (long)(h * 128 + (wave << 5) + (lane >> 3)) * M +
                   (((lane & 7) ^ ((lane >> 3) & 7)) << 3);
  bf16* vsl = &Vts[(wave << 5) * 64 + lane * 8];

  // P-write addresses (8, hoisted): tiles (mt, n2)
  int waddr[2][4];
#pragma unroll
  for (int mt = 0; mt < 2; mt++)
#pragma unroll
    for (int n2 = 0; n2 < 4; n2++) {
      int n = sw_n * 64 + n2 * 16 + ln;
      int mb8 = sw_m * 4 + mt * 2 + (quad >> 1);
      waddr[mt][n2] = n * 64 + ((mb8 ^ (n & 7)) << 3) + ((quad & 1) << 2);
    }

  for (int m0 = 0; m0 < M; m0 += 64) {
    __syncthreads();
#pragma unroll
    for (int i = 0; i < 4; i++) {
      gload_lds16(kg + (long)(m0 + i * 4) * E + kc[i], ksl + i * 4 * 128);
      gload_lds16(vg + m0 + (long)i * 8 * M, vsl + i * 8 * 64);
    }
    __syncthreads();

    // S^T = K · Q^T  (D rows = m, cols = n); wave: m32 x n64
    f32x4 sacc[2][4] = {};
#pragma unroll
    for (int ks = 0; ks < 4; ks++) {
      bf16x8 af[2];
#pragma unroll
      for (int mt = 0; mt < 2; mt++)
        af[mt] = *(const bf16x8*)&Ks[(sw_m * 32 + mt * 16 + ln) * 128 +
                                     (((ks * 4 + quad) ^ ln) << 3)];
#pragma unroll
      for (int mt = 0; mt < 2; mt++)
#pragma unroll
        for (int n2 = 0; n2 < 4; n2++) sacc[mt][n2] = MFMA(af[mt], qf[n2][ks], sacc[mt][n2]);
    }

    // silu + pack 4 m-consecutive values -> one ds_write_b64 per tile
#pragma unroll
    for (int mt = 0; mt < 2; mt++)
#pragma unroll
      for (int n2 = 0; n2 < 4; n2++) {
        bf16x4 p;
#pragma unroll
        for (int r = 0; r < 4; r++) p[r] = (bf16)fast_silu(sacc[mt][n2][r]);
        *(bf16x4*)&Ps[waddr[mt][n2]] = p;
      }
    __syncthreads();

    // O += P · V^T; wave: n64 x dv64
#pragma unroll
    for (int ks = 0; ks < 2; ks++) {
      const int so = ((ks * 4 + quad) ^ (ln & 7)) << 3;
      bf16x8 pf[4], vf[4];
#pragma unroll
      for (int n2 = 0; n2 < 4; n2++)
        pf[n2] = *(const bf16x8*)&Ps[(pw_n * 64 + n2 * 16 + ln) * 64 + so];
#pragma unroll
      for (int dt = 0; dt < 4; dt++)
        vf[dt] = *(const bf16x8*)&Vts[(pw_dv * 64 + dt * 16 + ln) * 64 + so];
#pragma unroll
      for (int n2 = 0; n2 < 4; n2++)
#pragma unroll
        for (int dt = 0; dt < 4; dt++) oacc[n2][dt] = MFMA(pf[n2], vf[dt], oacc[n2][dt]);
    }
  }

  // Epilogue: gated = gate * (O * scale); gate_io aliases glin/gated
  bf16* gio = gate_io + n0 * E + h * 128;
#pragma unroll
  for (int n2 = 0; n2 < 4; n2++)
#pragma unroll
    for (int dt = 0; dt < 4; dt++)
#pragma unroll
      for (int r = 0; r < 4; r++) {
        int n = pw_n * 64 + n2 * 16 + quad * 4 + r;
        int dv = pw_dv * 64 + dt * 16 + ln;
        float g = (float)gio[(long)n * E + dv];
        gio[(long)n * E + dv] = (bf16)(g * oacc[n2][dt][r] * scale);
      }
}

// ---------------------------------------------------------------------------
extern "C" void kernel_launch(void* const* d_in, const int* in_sizes, int n_in,
                              void* d_out, int out_size, void* d_ws, size_t ws_size,
                              hipStream_t stream) {
  const float* x = (const float*)d_in[0];
  const float* Wq = (const float*)d_in[1];
  const float* kw = (const float*)d_in[2];
  const float* vw = (const float*)d_in[3];
  const float* Wg = (const float*)d_in[4];
  const float* Wout = (const float*)d_in[5];
  float* out = (float*)d_out;
  bf16* ws = (bf16*)d_ws;

  // 5 slots x 8,388,608 bf16 = 83.9 MB
  bf16* S0 = ws;              // xb, then kwb
  bf16* S1 = ws + 8388608;    // Wqb | Wgb, then Woutb
  bf16* S2 = ws + 16777216;   // vt
  bf16* S3 = ws + 25165824;   // q (pre-scaled)
  bf16* S4 = ws + 33554432;   // glin (silu'd) -> gated in-place
  bf16* Wgb = S1 + 4194304;

  cvt_bf16<<<8192, 256, 0, stream>>>(x, S0, 8388608);
  cvt_bf16<<<4096, 256, 0, stream>>>(Wq, S1, 4194304);
  cvt_bf16<<<4096, 256, 0, stream>>>(Wg, Wgb, 4194304);
  transpose_v_cvt<<<dim3(64, 32), 256, 0, stream>>>(vw, S2);
  // q = qscale*(x Wq^T); glin = silu(x Wg^T)  — one dual GEMM
  gemm_bt<3><<<dim3(32, 32), 256, 0, stream>>>(S0, S1, Wgb, S3, S4, (float*)nullptr, 4096, 2048,
                                               2048);
  cvt_bf16<<<8192, 256, 0, stream>>>(kw, S0, 8388608);  // xb dead -> kwb
  // gated = glin * scale * (silu(q K^T) V), in-place on S4
  attn_fused<<<512, 256, 0, stream>>>(S3, S0, S2, S4);
  cvt_bf16<<<4096, 256, 0, stream>>>(Wout, S1, 4194304);  // Wq/Wg dead -> Woutb
  // out = gated Wout^T (fp32)
  gemm_bt<2><<<dim3(16, 32), 256, 0, stream>>>(S4, S1, (const bf16*)nullptr, (bf16*)nullptr,
                                               (bf16*)nullptr, out, 4096, 2048, 2048);
}